// Round 5
// baseline (859.227 us; speedup 1.0000x reference)
//
#include <hip/hip_runtime.h>
#include <hip/hip_bf16.h>
#include <math.h>

#define IGNORE_INDEX (-100)

constexpr int BT = 2048, H = 4096, V = 32000;
constexpr int BM = 256, BN = 256, BK = 64;
constexpr int KT = H / BK;            // 64 k-tiles
constexpr int MT2 = BT / BM;          // 8
constexpr int NT2 = V / BN;           // 125
constexpr int NCHUNK = NT2 * 4;       // 500 partial chunks/row (64 cols each)

typedef __bf16 bf16x8 __attribute__((ext_vector_type(8)));
typedef float f32x16 __attribute__((ext_vector_type(16)));

__device__ __forceinline__ void gload_lds16(const __bf16* g, short* l) {
  __builtin_amdgcn_global_load_lds(
      (const __attribute__((address_space(1))) unsigned int*)(g),
      (__attribute__((address_space(3))) unsigned int*)(l), 16, 0, 0);
}

#define BAR()        asm volatile("s_barrier" ::: "memory")
#define WAIT_LGKM0() asm volatile("s_waitcnt lgkmcnt(0)" ::: "memory")
#define WAIT_VM(N)   asm volatile("s_waitcnt vmcnt(" #N ")" ::: "memory")

// ---------------------------------------------------------------------------
// fp32 -> bf16 bulk convert
// ---------------------------------------------------------------------------
__global__ __launch_bounds__(256)
void convert_bf16(const float* __restrict__ src, __bf16* __restrict__ dst,
                  int n8) {
  int i = blockIdx.x * blockDim.x + threadIdx.x;
  const int stride = gridDim.x * blockDim.x;
  for (; i < n8; i += stride) {
    const float4 f0 = ((const float4*)src)[2 * i];
    const float4 f1 = ((const float4*)src)[2 * i + 1];
    bf16x8 v;
    v[0] = (__bf16)f0.x; v[1] = (__bf16)f0.y;
    v[2] = (__bf16)f0.z; v[3] = (__bf16)f0.w;
    v[4] = (__bf16)f1.x; v[5] = (__bf16)f1.y;
    v[6] = (__bf16)f1.z; v[7] = (__bf16)f1.w;
    ((bf16x8*)dst)[i] = v;
  }
}

// ---------------------------------------------------------------------------
// 256x256 GEMM, 32x32x16 MFMA, 4 phases per 2 K-tiles, 1 barrier per phase.
// Hazard audit (stage at p safe iff region's readers drained >=1 barrier
// before stage issue): ph1 stages buf1.kh0 (last read prev-ph3; prev-ph4 BAR
// between) / ph2: buf1.kh1 (prev-ph4; ph1 BAR) / ph3: buf0.kh0 (ph1; ph2 BAR)
// / ph4: buf0.kh1 (ph2; ph3 BAR). Uniform VM(4) per phase drains phase p-1's
// 4 stage-loads before BAR -> readable at p+1 (1-phase landing margin).
// ---------------------------------------------------------------------------
__global__ __launch_bounds__(512, 2)
void gemm_lse_32(const __bf16* __restrict__ Wb,   // (V,H) bf16
                 const __bf16* __restrict__ Xb,   // (BT,H) bf16
                 const int* __restrict__ target,
                 const float* __restrict__ bias,
                 float* __restrict__ pM, float* __restrict__ pS,
                 float* __restrict__ gold)
{
  // flat: [buf][kh][256 rows][32 k-shorts]; buf stride 16384, kh stride 8192
  __shared__ short As[4 * 8192];
  __shared__ short Bs[4 * 8192];

  const int tid  = threadIdx.x;
  const int lane = tid & 63;
  const int wid  = tid >> 6;
  const int wr   = wid >> 2;        // 0..1 : rows [wr*128, +128)
  const int wcol = wid & 3;         // 0..3 : cols [wcol*64, +64)

  // XCD swizzle: nwg = 1000 = 8*125, bijective
  const int bid = (int)blockIdx.x;
  const int swz = (bid & 7) * 125 + (bid >> 3);
  const int mt = swz & (MT2 - 1);
  const int nt = swz >> 3;
  const int m0 = mt * BM, n0 = nt * BN;

  const int l31 = lane & 31;
  const int h   = lane >> 5;
  // 16B-slot XOR swizzle on (row>>1)&3; row%8 == l31%8 for all frag rows ->
  // slot is lane-only; two per-lane bases (ks=0: slot h, ks=1: slot 2+h)
  const int swz4 = (l31 >> 1) & 3;
  const int sl0 = ((h ^ swz4) & 3) << 3;
  const int sl1 = (((2 + h) ^ swz4) & 3) << 3;
  const int abase0 = (wr * 128 + l31) * 32 + sl0;
  const int abase1 = (wr * 128 + l31) * 32 + sl1;
  const int bbase0 = (wcol * 64 + l31) * 32 + sl0;
  const int bbase1 = (wcol * 64 + l31) * 32 + sl1;

  // staging: lane covers row (l>>2), 16B slot (l&3); source pre-swizzled
  const int srow = lane >> 2;
  const int sj8  = (((lane & 3) ^ ((lane >> 3) & 3)) << 3);

  const __bf16* ax0 = Xb + (size_t)(m0 + wid * 16 + srow) * H + sj8;
  const __bf16* ax1 = ax0 + (size_t)128 * H;
  const __bf16* bx0 = Wb + (size_t)(n0 + wid * 16 + srow) * H + sj8;
  const __bf16* bx1 = bx0 + (size_t)128 * H;

  f32x16 acc[8] = {};                 // [mi*2 + ni]
  bf16x8 a_[4][2], b_[2][2];

#define STAGE_A(BUF, KH, DT)                                                  \
  { gload_lds16(ax0 + (DT) * BK + (KH) * 32,                                  \
                &As[(BUF) * 16384 + (KH) * 8192 + wid * 512]);                \
    gload_lds16(ax1 + (DT) * BK + (KH) * 32,                                  \
                &As[(BUF) * 16384 + (KH) * 8192 + (8 + wid) * 512]); }

#define STAGE_B(BUF, KH, DT)                                                  \
  { gload_lds16(bx0 + (DT) * BK + (KH) * 32,                                  \
                &Bs[(BUF) * 16384 + (KH) * 8192 + wid * 512]);                \
    gload_lds16(bx1 + (DT) * BK + (KH) * 32,                                  \
                &Bs[(BUF) * 16384 + (KH) * 8192 + (8 + wid) * 512]); }

#define READ_AB(BUF, KH)                                                      \
  { _Pragma("unroll")                                                         \
    for (int mi = 0; mi < 4; ++mi) {                                          \
      a_[mi][0] = *(const bf16x8*)&As[(BUF) * 16384 + (KH) * 8192 +           \
                                      mi * 1024 + abase0];                    \
      a_[mi][1] = *(const bf16x8*)&As[(BUF) * 16384 + (KH) * 8192 +           \
                                      mi * 1024 + abase1];                    \
    }                                                                         \
    _Pragma("unroll")                                                         \
    for (int ni = 0; ni < 2; ++ni) {                                          \
      b_[ni][0] = *(const bf16x8*)&Bs[(BUF) * 16384 + (KH) * 8192 +           \
                                      ni * 1024 + bbase0];                    \
      b_[ni][1] = *(const bf16x8*)&Bs[(BUF) * 16384 + (KH) * 8192 +           \
                                      ni * 1024 + bbase1];                    \
    } }

#define MFMA32()                                                              \
  { __builtin_amdgcn_s_setprio(1);                                            \
    _Pragma("unroll")                                                         \
    for (int mi = 0; mi < 4; ++mi)                                            \
      _Pragma("unroll")                                                       \
      for (int ni = 0; ni < 2; ++ni) {                                        \
        acc[mi * 2 + ni] = __builtin_amdgcn_mfma_f32_32x32x16_bf16(           \
            a_[mi][0], b_[ni][0], acc[mi * 2 + ni], 0, 0, 0);                 \
        acc[mi * 2 + ni] = __builtin_amdgcn_mfma_f32_32x32x16_bf16(           \
            a_[mi][1], b_[ni][1], acc[mi * 2 + ni], 0, 0, 0);                 \
      }                                                                       \
    __builtin_amdgcn_s_setprio(0); }

  // ---- prologue: tile0 (buf0) fully staged; buf1 is staged in ph1/ph2
  STAGE_A(0, 0, 0); STAGE_B(0, 0, 0); STAGE_A(0, 1, 0); STAGE_B(0, 1, 0);
  WAIT_VM(0);
  BAR();

  // ---- main loop: 2 K-tiles/iter, 4 phases, 1 barrier each
  for (int t = 0; t <= KT - 4; t += 2) {
    // ph1: compute (buf0, kh0); stage buf1.kh0 <- (t+1).kh0
    READ_AB(0, 0); STAGE_A(1, 0, 1); STAGE_B(1, 0, 1);
    WAIT_VM(4); BAR(); WAIT_LGKM0(); MFMA32();
    // ph2: (buf0, kh1); stage buf1.kh1 <- (t+1).kh1
    READ_AB(0, 1); STAGE_A(1, 1, 1); STAGE_B(1, 1, 1);
    WAIT_VM(4); BAR(); WAIT_LGKM0(); MFMA32();
    // ph3: (buf1, kh0); stage buf0.kh0 <- (t+2).kh0
    READ_AB(1, 0); STAGE_A(0, 0, 2); STAGE_B(0, 0, 2);
    WAIT_VM(4); BAR(); WAIT_LGKM0(); MFMA32();
    // ph4: (buf1, kh1); stage buf0.kh1 <- (t+2).kh1
    READ_AB(1, 1); STAGE_A(0, 1, 2); STAGE_B(0, 1, 2);
    WAIT_VM(4); BAR(); WAIT_LGKM0(); MFMA32();

    ax0 += 2 * BK; ax1 += 2 * BK; bx0 += 2 * BK; bx1 += 2 * BK;
  }

  // ---- tail: tiles KT-2 (buf0), KT-1 (buf1)
  READ_AB(0, 0); STAGE_A(1, 0, 1); STAGE_B(1, 0, 1);
  WAIT_VM(4); BAR(); WAIT_LGKM0(); MFMA32();
  READ_AB(0, 1); STAGE_A(1, 1, 1); STAGE_B(1, 1, 1);
  WAIT_VM(4); BAR(); WAIT_LGKM0(); MFMA32();
  READ_AB(1, 0);
  WAIT_VM(0); BAR(); WAIT_LGKM0(); MFMA32();
  READ_AB(1, 1);
  WAIT_LGKM0(); MFMA32();

#undef STAGE_A
#undef STAGE_B
#undef READ_AB
#undef MFMA32

  // ---- epilogue (32x32 C/D layout: col=lane&31, row=(r&3)+8*(r>>2)+4*h)
  const int colbase = n0 + wcol * 64;
  float bv[2];
#pragma unroll
  for (int ni = 0; ni < 2; ++ni) bv[ni] = bias[colbase + ni * 32 + l31];

  const int chunk = nt * 4 + wcol;
#pragma unroll
  for (int mi = 0; mi < 4; ++mi) {
#pragma unroll
    for (int r = 0; r < 16; ++r) {
      const int row = m0 + wr * 128 + mi * 32 + (r & 3) + 8 * (r >> 2) + 4 * h;
      const float v0 = acc[mi * 2 + 0][r] + bv[0];
      const float v1 = acc[mi * 2 + 1][r] + bv[1];
      float mx = fmaxf(v0, v1);
#pragma unroll
      for (int d = 1; d < 32; d <<= 1) mx = fmaxf(mx, __shfl_xor(mx, d));
      float s = expf(v0 - mx) + expf(v1 - mx);
#pragma unroll
      for (int d = 1; d < 32; d <<= 1) s += __shfl_xor(s, d);
      if (l31 == 0) {
        pM[(size_t)row * NCHUNK + chunk] = mx;
        pS[(size_t)row * NCHUNK + chunk] = s;
      }
      const int t = target[row];
      const int d0 = t - colbase;
      if (d0 >= 0 && d0 < 64 && l31 == (d0 & 31)) {
        gold[row] = (d0 >> 5) ? v1 : v0;
      }
    }
  }
}

// one wave per row: combine 500 (max, sumexp) chunks -> rowterm
__global__ __launch_bounds__(256)
void reduce_lse(const float* __restrict__ pM, const float* __restrict__ pS,
                const float* __restrict__ gold, const int* __restrict__ target,
                const float* __restrict__ lw, float* __restrict__ rowterm)
{
  const int wid = threadIdx.x >> 6, lane = threadIdx.x & 63;
  const int row = blockIdx.x * 4 + wid;
  if (row >= BT) return;
  const float* pm = pM + (size_t)row * NCHUNK;
  const float* ps = pS + (size_t)row * NCHUNK;
  float m = -INFINITY;
  for (int c2 = lane; c2 < NCHUNK; c2 += 64) m = fmaxf(m, pm[c2]);
#pragma unroll
  for (int d = 1; d < 64; d <<= 1) m = fmaxf(m, __shfl_xor(m, d));
  float s = 0.f;
  for (int c2 = lane; c2 < NCHUNK; c2 += 64) s += ps[c2] * expf(pm[c2] - m);
#pragma unroll
  for (int d = 1; d < 64; d <<= 1) s += __shfl_xor(s, d);
  if (lane == 0) {
    const int t = target[row];
    float term = 0.f;
    if (t != IGNORE_INDEX) term = (m + logf(s) - gold[row]) * lw[row];
    rowterm[row] = term;
  }
}

// single-block deterministic finalize
__global__ __launch_bounds__(256)
void finalize(const float* __restrict__ rowterm, const int* __restrict__ target,
              const float* __restrict__ rsw, const int* __restrict__ gas,
              float* __restrict__ out)
{
  __shared__ float sred[4];
  __shared__ int cred[4];
  const int tid = threadIdx.x;
  float s = 0.f;
  int cnt = 0;
  for (int i = tid; i < BT; i += 256) {
    s += rowterm[i];
    cnt += (target[i] != IGNORE_INDEX) ? 1 : 0;
  }
#pragma unroll
  for (int d = 1; d < 64; d <<= 1) {
    s += __shfl_xor(s, d);
    cnt += __shfl_xor(cnt, d);
  }
  const int wid = tid >> 6, lane = tid & 63;
  if (lane == 0) { sred[wid] = s; cred[wid] = cnt; }
  __syncthreads();
  if (tid == 0) {
    const float st = sred[0] + sred[1] + sred[2] + sred[3];
    const int ct = cred[0] + cred[1] + cred[2] + cred[3];
    const float n = (float)((ct > 0) ? ct : 1);
    const float rs = rsw[0];
    float loss = (rs == 0.f) ? 0.f : (st / n) / rs;
    loss /= (float)gas[0];
    out[0] = loss;
  }
}

extern "C" void kernel_launch(void* const* d_in, const int* in_sizes, int n_in,
                              void* d_out, int out_size, void* d_ws, size_t ws_size,
                              hipStream_t stream)
{
  const float* Wt     = (const float*)d_in[0];  // lin_weight (V,H)
  const float* X      = (const float*)d_in[1];  // _input (BT,H)
  const int*   target = (const int*)d_in[2];
  const float* bias   = (const float*)d_in[3];
  const float* lw     = (const float*)d_in[4];
  const float* rsw    = (const float*)d_in[5];
  const int*   gas    = (const int*)d_in[6];
  float* out = (float*)d_out;

  const size_t nW = (size_t)V * H, nX = (size_t)BT * H;

  __bf16* Wb = (__bf16*)d_ws;
  __bf16* Xb = Wb + nW;
  float* pM = (float*)(Xb + nX);
  float* pS = pM + (size_t)BT * NCHUNK;
  float* gold = pS + (size_t)BT * NCHUNK;
  float* rowterm = gold + BT;

  convert_bf16<<<dim3(2048), dim3(256), 0, stream>>>(Wt, Wb, (int)(nW / 8));
  convert_bf16<<<dim3(256), dim3(256), 0, stream>>>(X, Xb, (int)(nX / 8));
  gemm_lse_32<<<dim3(MT2 * NT2), dim3(512), 0, stream>>>(Wb, Xb, target,
                                                         bias, pM, pS, gold);
  reduce_lse<<<dim3(BT / 4), dim3(256), 0, stream>>>(pM, pS, gold, target, lw,
                                                     rowterm);
  finalize<<<dim3(1), dim3(256), 0, stream>>>(rowterm, target, rsw, gas, out);
}

// Round 6
// 738.329 us; speedup vs baseline: 1.1637x; 1.1637x over previous
//
#include <hip/hip_runtime.h>
#include <hip/hip_bf16.h>
#include <math.h>

#define IGNORE_INDEX (-100)

constexpr int BT = 2048, H = 4096, V = 32000;
constexpr int BM = 256, BN = 256, BK = 64;
constexpr int KT = H / BK;            // 64 k-tiles
constexpr int MT2 = BT / BM;          // 8
constexpr int NT2 = V / BN;           // 125
constexpr int NCHUNK = NT2 * 4;       // 500 partial chunks/row (64 cols each)

typedef __bf16 bf16x8 __attribute__((ext_vector_type(8)));
typedef float f32x4 __attribute__((ext_vector_type(4)));

__device__ __forceinline__ void gload_lds16(const __bf16* g, short* l) {
  __builtin_amdgcn_global_load_lds(
      (const __attribute__((address_space(1))) unsigned int*)(g),
      (__attribute__((address_space(3))) unsigned int*)(l), 16, 0, 0);
}

#define BAR()        asm volatile("s_barrier" ::: "memory")
#define WAIT_LGKM0() asm volatile("s_waitcnt lgkmcnt(0)" ::: "memory")
#define WAIT_VM(N)   asm volatile("s_waitcnt vmcnt(" #N ")" ::: "memory")

// ---------------------------------------------------------------------------
// fp32 -> bf16 bulk convert
// ---------------------------------------------------------------------------
__global__ __launch_bounds__(256)
void convert_bf16(const float* __restrict__ src, __bf16* __restrict__ dst,
                  int n8) {
  int i = blockIdx.x * blockDim.x + threadIdx.x;
  const int stride = gridDim.x * blockDim.x;
  for (; i < n8; i += stride) {
    const float4 f0 = ((const float4*)src)[2 * i];
    const float4 f1 = ((const float4*)src)[2 * i + 1];
    bf16x8 v;
    v[0] = (__bf16)f0.x; v[1] = (__bf16)f0.y;
    v[2] = (__bf16)f0.z; v[3] = (__bf16)f0.w;
    v[4] = (__bf16)f1.x; v[5] = (__bf16)f1.y;
    v[6] = (__bf16)f1.z; v[7] = (__bf16)f1.w;
    ((bf16x8*)dst)[i] = v;
  }
}

// ---------------------------------------------------------------------------
// 256x256 bf16 GEMM, 16x16x32 MFMA, m201 st_16x32 LDS layout.
// LDS: per operand, [buf][half][128 rows][64 k] bf16 (128B rows). Swizzle:
// 16B-quad ^= ((row>>2)&1)<<1  == byte ^= ((row&4)?32:0)  (st_16x32).
// Staged via linear-dest global_load_lds with INVERSE-swizzled per-lane
// global source quad (both-sides-or-neither, rule #21).
// Schedule: 8 phases / 2 K-tiles, 1 barrier/phase (r4-verified skeleton).
// Staging: 2 regions (4 gloads) at P1,P2,P5,P6; VM(4)@P2,P6; VM(0)@P4,P8.
//  stage->first-read gaps: B(b1)@P1->P5(4), B(b1)@P2... A(b1)@P2->P5(3..),
//  all >=2 barriers after the draining VM. Overwrite gaps: B(b1)@P1 after
//  last read P7_prev (BAR P8 between); A(b1)@P2 after P8_prev (BAR P1);
//  B(b0)@P5 after P3 (BAR P4); A(b0)@P6 after P4 (BAR P5). All >=1 barrier.
// ---------------------------------------------------------------------------
__global__ __launch_bounds__(512, 2)
void gemm_lse_sw(const __bf16* __restrict__ Wb,   // (V,H) bf16
                 const __bf16* __restrict__ Xb,   // (BT,H) bf16
                 const int* __restrict__ target,
                 const float* __restrict__ bias,
                 float* __restrict__ pM, float* __restrict__ pS,
                 float* __restrict__ gold)
{
  // flat shorts: region(buf,half) = 8192 shorts (16KB); buf stride 16384
  __shared__ short As[32768];
  __shared__ short Bs[32768];

  const int tid  = threadIdx.x;
  const int lane = tid & 63;
  const int wid  = tid >> 6;
  const int wr   = wid >> 2;        // 0..1 : A half, rows [wr*128, +128)
  const int wcol = wid & 3;         // 0..3 : cols [wcol*64, +64)

  // XCD swizzle: nwg = 1000 = 8*125, bijective
  const int bid = (int)blockIdx.x;
  const int swz = (bid & 7) * 125 + (bid >> 3);
  const int mt = swz & (MT2 - 1);
  const int nt = swz >> 3;
  const int m0 = mt * BM, n0 = nt * BN;

  const int l15 = lane & 15;
  const int j4  = lane >> 4;                  // k-quad within 32-k window
  const int xq  = ((l15 >> 2) & 1) << 1;      // st_16x32: row-bit2 -> quad-bit1
  const int aq  = (j4 ^ xq) & 3;              // swizzled read quad
  // per-lane ds_read bases (shorts); all other indexing is compile-time imm
  const int abase = wr * 8192 + l15 * 64 + aq * 8;
  const int bbase = (wcol >> 1) * 8192 + ((wcol & 1) * 64 + l15) * 64 + aq * 8;

  // staging: lane l covers row (l>>3) of an 8-row chunk, physical quad l&7;
  // inverse-swizzled source quad = (l&7) ^ ((rowbit2 = l>>5)<<1)
  const int sq = ((lane & 7) ^ (((lane >> 5) & 1) << 1)) & 7;

  const __bf16* asrc =
      Xb + (size_t)(m0 + wid * 16 + (lane >> 3)) * H + sq * 8;
  const __bf16* bsrc =
      Wb + (size_t)(n0 + wid * 16 + (lane >> 3)) * H + sq * 8;

  f32x4 acc[8][4] = {};
  bf16x8 af[4], bfr[4];

  // stage BOTH halves of operand region set (buf) for tile t+DT: 4 gloads
#define STAGE_A2(BUF, DT)                                                     \
  { _Pragma("unroll")                                                         \
    for (int ah = 0; ah < 2; ++ah)                                            \
      _Pragma("unroll")                                                       \
      for (int g = 0; g < 2; ++g)                                             \
        gload_lds16(asrc + (size_t)(ah * 128 + g * 8) * H + (DT) * BK,        \
                    &As[(BUF) * 16384 + ah * 8192 + wid * 1024 + g * 512]); }

#define STAGE_B2(BUF, DT)                                                     \
  { _Pragma("unroll")                                                         \
    for (int bh = 0; bh < 2; ++bh)                                            \
      _Pragma("unroll")                                                       \
      for (int g = 0; g < 2; ++g)                                             \
        gload_lds16(bsrc + (size_t)(bh * 128 + g * 8) * H + (DT) * BK,        \
                    &Bs[(BUF) * 16384 + bh * 8192 + wid * 1024 + g * 512]); }

#define READ_A(BUF, KK, MH)                                                   \
  { _Pragma("unroll")                                                         \
    for (int mi = 0; mi < 4; ++mi)                                            \
      af[mi] = *(const bf16x8*)&As[(BUF) * 16384 + abase + (MH) * 4096 +      \
                                   mi * 1024 + (KK) * 32]; }

#define READ_B(BUF, KK)                                                       \
  { _Pragma("unroll")                                                         \
    for (int ni = 0; ni < 4; ++ni)                                            \
      bfr[ni] = *(const bf16x8*)&Bs[(BUF) * 16384 + bbase + ni * 1024 +       \
                                    (KK) * 32]; }

#define MFMA16(MH)                                                            \
  { __builtin_amdgcn_s_setprio(1);                                            \
    _Pragma("unroll")                                                         \
    for (int mi = 0; mi < 4; ++mi)                                            \
      _Pragma("unroll")                                                       \
      for (int ni = 0; ni < 4; ++ni)                                          \
        acc[(MH) * 4 + mi][ni] = __builtin_amdgcn_mfma_f32_16x16x32_bf16(     \
            af[mi], bfr[ni], acc[(MH) * 4 + mi][ni], 0, 0, 0);                \
    __builtin_amdgcn_s_setprio(0); }

  // ---- prologue: stage tile0 (buf0) fully, drain, barrier
  STAGE_B2(0, 0); STAGE_A2(0, 0);
  WAIT_VM(0);
  BAR();

  // ---- main loop: 2 K-tiles/iter, 8 phases, 1 barrier each
  for (int t = 0; t <= KT - 4; t += 2) {
    // P1: compute (b0,k0,m0); stage B(b1) <- t+1
    STAGE_B2(1, 1);
    READ_A(0, 0, 0); READ_B(0, 0);
    BAR(); WAIT_LGKM0(); MFMA16(0);
    // P2: (b0,k0,m1); stage A(b1) <- t+1; VM(4) drains P1's B(b1)
    STAGE_A2(1, 1);
    WAIT_VM(4);
    READ_A(0, 0, 1);
    BAR(); WAIT_LGKM0(); MFMA16(1);
    // P3: (b0,k1,m0)
    READ_A(0, 1, 0); READ_B(0, 1);
    BAR(); WAIT_LGKM0(); MFMA16(0);
    // P4: (b0,k1,m1); VM(0) drains P2's A(b1) -> buf1 readable at P5
    WAIT_VM(0);
    READ_A(0, 1, 1);
    BAR(); WAIT_LGKM0(); MFMA16(1);
    // P5: (b1,k0,m0); stage B(b0) <- t+2
    STAGE_B2(0, 2);
    READ_A(1, 0, 0); READ_B(1, 0);
    BAR(); WAIT_LGKM0(); MFMA16(0);
    // P6: (b1,k0,m1); stage A(b0) <- t+2; VM(4) drains P5's B(b0)
    STAGE_A2(0, 2);
    WAIT_VM(4);
    READ_A(1, 0, 1);
    BAR(); WAIT_LGKM0(); MFMA16(1);
    // P7: (b1,k1,m0)
    READ_A(1, 1, 0); READ_B(1, 1);
    BAR(); WAIT_LGKM0(); MFMA16(0);
    // P8: (b1,k1,m1); VM(0) drains P6's A(b0) -> buf0 readable at P1'
    WAIT_VM(0);
    READ_A(1, 1, 1);
    BAR(); WAIT_LGKM0(); MFMA16(1);

    asrc += 2 * BK; bsrc += 2 * BK;
  }

  // ---- tail: tiles KT-2 (buf0), KT-1 (buf1)
  STAGE_B2(1, 1);
  READ_A(0, 0, 0); READ_B(0, 0);
  BAR(); WAIT_LGKM0(); MFMA16(0);
  STAGE_A2(1, 1);
  WAIT_VM(4);
  READ_A(0, 0, 1);
  BAR(); WAIT_LGKM0(); MFMA16(1);
  READ_A(0, 1, 0); READ_B(0, 1);
  BAR(); WAIT_LGKM0(); MFMA16(0);
  WAIT_VM(0);
  READ_A(0, 1, 1);
  BAR(); WAIT_LGKM0(); MFMA16(1);
  READ_A(1, 0, 0); READ_B(1, 0);
  BAR(); WAIT_LGKM0(); MFMA16(0);
  READ_A(1, 0, 1);
  BAR(); WAIT_LGKM0(); MFMA16(1);
  READ_A(1, 1, 0); READ_B(1, 1);
  BAR(); WAIT_LGKM0(); MFMA16(0);
  READ_A(1, 1, 1);
  WAIT_LGKM0(); MFMA16(1);

#undef STAGE_A2
#undef STAGE_B2
#undef READ_A
#undef READ_B
#undef MFMA16

  // ---- epilogue: bias + per-row (max, sum-exp) over this wave's 64 cols
  const int g = lane >> 4;          // row group 0..3
  const int c = lane & 15;          // col-in-fragment
  const int colbase = n0 + wcol * 64;
  float bv[4];
#pragma unroll
  for (int ni = 0; ni < 4; ++ni) bv[ni] = bias[colbase + ni * 16 + c];

  const int chunk = nt * 4 + wcol;
#pragma unroll
  for (int mi = 0; mi < 8; ++mi) {
#pragma unroll
    for (int r = 0; r < 4; ++r) {
      const int row = m0 + wr * 128 + mi * 16 + g * 4 + r;
      const float v0 = acc[mi][0][r] + bv[0];
      const float v1 = acc[mi][1][r] + bv[1];
      const float v2 = acc[mi][2][r] + bv[2];
      const float v3 = acc[mi][3][r] + bv[3];
      float mx = fmaxf(fmaxf(v0, v1), fmaxf(v2, v3));
#pragma unroll
      for (int d = 1; d < 16; d <<= 1) mx = fmaxf(mx, __shfl_xor(mx, d));
      float s = expf(v0 - mx) + expf(v1 - mx) + expf(v2 - mx) + expf(v3 - mx);
#pragma unroll
      for (int d = 1; d < 16; d <<= 1) s += __shfl_xor(s, d);
      if (c == 0) {
        pM[(size_t)row * NCHUNK + chunk] = mx;
        pS[(size_t)row * NCHUNK + chunk] = s;
      }
      const int t = target[row];
      const int d0 = t - colbase;
      if (d0 >= 0 && d0 < 64 && c == (d0 & 15)) {
        const int nw = d0 >> 4;
        const float gv = (nw == 0) ? v0 : (nw == 1) ? v1 : (nw == 2) ? v2 : v3;
        gold[row] = gv;
      }
    }
  }
}

// one wave per row: combine 500 (max, sumexp) chunks -> rowterm
__global__ __launch_bounds__(256)
void reduce_lse(const float* __restrict__ pM, const float* __restrict__ pS,
                const float* __restrict__ gold, const int* __restrict__ target,
                const float* __restrict__ lw, float* __restrict__ rowterm)
{
  const int wid = threadIdx.x >> 6, lane = threadIdx.x & 63;
  const int row = blockIdx.x * 4 + wid;
  if (row >= BT) return;
  const float* pm = pM + (size_t)row * NCHUNK;
  const float* ps = pS + (size_t)row * NCHUNK;
  float m = -INFINITY;
  for (int c2 = lane; c2 < NCHUNK; c2 += 64) m = fmaxf(m, pm[c2]);
#pragma unroll
  for (int d = 1; d < 64; d <<= 1) m = fmaxf(m, __shfl_xor(m, d));
  float s = 0.f;
  for (int c2 = lane; c2 < NCHUNK; c2 += 64) s += ps[c2] * expf(pm[c2] - m);
#pragma unroll
  for (int d = 1; d < 64; d <<= 1) s += __shfl_xor(s, d);
  if (lane == 0) {
    const int t = target[row];
    float term = 0.f;
    if (t != IGNORE_INDEX) term = (m + logf(s) - gold[row]) * lw[row];
    rowterm[row] = term;
  }
}

// single-block deterministic finalize
__global__ __launch_bounds__(256)
void finalize(const float* __restrict__ rowterm, const int* __restrict__ target,
              const float* __restrict__ rsw, const int* __restrict__ gas,
              float* __restrict__ out)
{
  __shared__ float sred[4];
  __shared__ int cred[4];
  const int tid = threadIdx.x;
  float s = 0.f;
  int cnt = 0;
  for (int i = tid; i < BT; i += 256) {
    s += rowterm[i];
    cnt += (target[i] != IGNORE_INDEX) ? 1 : 0;
  }
#pragma unroll
  for (int d = 1; d < 64; d <<= 1) {
    s += __shfl_xor(s, d);
    cnt += __shfl_xor(cnt, d);
  }
  const int wid = tid >> 6, lane = tid & 63;
  if (lane == 0) { sred[wid] = s; cred[wid] = cnt; }
  __syncthreads();
  if (tid == 0) {
    const float st = sred[0] + sred[1] + sred[2] + sred[3];
    const int ct = cred[0] + cred[1] + cred[2] + cred[3];
    const float n = (float)((ct > 0) ? ct : 1);
    const float rs = rsw[0];
    float loss = (rs == 0.f) ? 0.f : (st / n) / rs;
    loss /= (float)gas[0];
    out[0] = loss;
  }
}

extern "C" void kernel_launch(void* const* d_in, const int* in_sizes, int n_in,
                              void* d_out, int out_size, void* d_ws, size_t ws_size,
                              hipStream_t stream)
{
  const float* Wt     = (const float*)d_in[0];  // lin_weight (V,H)
  const float* X      = (const float*)d_in[1];  // _input (BT,H)
  const int*   target = (const int*)d_in[2];
  const float* bias   = (const float*)d_in[3];
  const float* lw     = (const float*)d_in[4];
  const float* rsw    = (const float*)d_in[5];
  const int*   gas    = (const int*)d_in[6];
  float* out = (float*)d_out;

  const size_t nW = (size_t)V * H, nX = (size_t)BT * H;

  __bf16* Wb = (__bf16*)d_ws;
  __bf16* Xb = Wb + nW;
  float* pM = (float*)(Xb + nX);
  float* pS = pM + (size_t)BT * NCHUNK;
  float* gold = pS + (size_t)BT * NCHUNK;
  float* rowterm = gold + BT;

  convert_bf16<<<dim3(2048), dim3(256), 0, stream>>>(Wt, Wb, (int)(nW / 8));
  convert_bf16<<<dim3(256), dim3(256), 0, stream>>>(X, Xb, (int)(nX / 8));
  gemm_lse_sw<<<dim3(MT2 * NT2), dim3(512), 0, stream>>>(Wb, Xb, target,
                                                         bias, pM, pS, gold);
  reduce_lse<<<dim3(BT / 4), dim3(256), 0, stream>>>(pM, pS, gold, target, lw,
                                                     rowterm);
  finalize<<<dim3(1), dim3(256), 0, stream>>>(rowterm, target, rsw, gas, out);
}